// Round 1
// baseline (713.867 us; speedup 1.0000x reference)
//
#include <hip/hip_runtime.h>

#define WAVE 64

// ---------------- edge dtype detection ----------------
// If edge_index is int64 (little-endian, values < 100000), every odd int32
// word is 0. If int32, odd words are random node ids (P[all 64 zero] ~ 0).
__global__ void gin_detect(const void* __restrict__ edge, int* __restrict__ flag, int E) {
    const int* p = (const int*)edge;
    int is64 = 1;
    int m = (E < 64) ? E : 64;
    for (int i = 0; i < m; ++i)
        if (p[2 * i + 1] != 0) is64 = 0;
    *flag = is64;
}

__device__ __forceinline__ void load_edge(const void* edge, int is64, int E, int e,
                                          int& s, int& d) {
    if (is64) {
        const long long* p = (const long long*)edge;
        s = (int)p[e];
        d = (int)p[E + e];
    } else {
        const int* p = (const int*)edge;
        s = p[e];
        d = p[E + e];
    }
}

// ---------------- CSR build ----------------
__global__ void gin_hist(const void* __restrict__ edge, const int* __restrict__ flag,
                         int* __restrict__ cnt, int E) {
    int e = blockIdx.x * blockDim.x + threadIdx.x;
    if (e >= E) return;
    int is64 = *flag;
    int s, d;
    load_edge(edge, is64, E, e, s, d);
    atomicAdd(&cnt[d], 1);
}

__global__ __launch_bounds__(256) void gin_scanA(const int* __restrict__ cnt,
                                                 int* __restrict__ rowptr,
                                                 int* __restrict__ chunksum, int n) {
    int tid = threadIdx.x;
    int gid = blockIdx.x * 256 + tid;
    int v = (gid < n) ? cnt[gid] : 0;
    int lane = tid & 63, wv = tid >> 6;
    int x = v;
    #pragma unroll
    for (int d = 1; d < 64; d <<= 1) {
        int y = __shfl_up(x, d, 64);
        if (lane >= d) x += y;
    }
    __shared__ int wsum[4];
    __shared__ int woff[4];
    if (lane == 63) wsum[wv] = x;
    __syncthreads();
    if (tid == 0) {
        int a = 0;
        #pragma unroll
        for (int i = 0; i < 4; ++i) { woff[i] = a; a += wsum[i]; }
        chunksum[blockIdx.x] = a;
    }
    __syncthreads();
    if (gid < n) rowptr[gid] = x - v + woff[wv];
}

__global__ __launch_bounds__(512) void gin_scanB(const int* __restrict__ s,
                                                 int* __restrict__ off, int nc) {
    int tid = threadIdx.x;
    int v = (tid < nc) ? s[tid] : 0;
    int lane = tid & 63, wv = tid >> 6;
    int x = v;
    #pragma unroll
    for (int d = 1; d < 64; d <<= 1) {
        int y = __shfl_up(x, d, 64);
        if (lane >= d) x += y;
    }
    __shared__ int wsum[8];
    __shared__ int woff[8];
    if (lane == 63) wsum[wv] = x;
    __syncthreads();
    if (tid == 0) {
        int a = 0;
        #pragma unroll
        for (int i = 0; i < 8; ++i) { woff[i] = a; a += wsum[i]; }
    }
    __syncthreads();
    if (tid < nc) off[tid] = x - v + woff[wv];
}

__global__ void gin_scanC(int* __restrict__ rowptr, const int* __restrict__ off,
                          int n, int E) {
    int gid = blockIdx.x * blockDim.x + threadIdx.x;
    if (gid < n) rowptr[gid] += off[gid >> 8];
    if (gid == 0) rowptr[n] = E;
}

__global__ void gin_copy(const int* __restrict__ r, int* __restrict__ c, int n) {
    int gid = blockIdx.x * blockDim.x + threadIdx.x;
    if (gid < n) c[gid] = r[gid];
}

__global__ void gin_fill(const void* __restrict__ edge, const int* __restrict__ flag,
                         int* __restrict__ cursor, int* __restrict__ col, int E) {
    int e = blockIdx.x * blockDim.x + threadIdx.x;
    if (e >= E) return;
    int is64 = *flag;
    int s, d;
    load_edge(edge, is64, E, e, s, d);
    int pos = atomicAdd(&cursor[d], 1);
    col[pos] = s;
}

// ---------------- gather: t[n] = (1+eps)*h[n] + sum_{j in N(n)} h[j] ----------------
// one wave per node, lane = feature (coalesced 256B per neighbor)
__global__ __launch_bounds__(256) void gin_gather(const float* __restrict__ h,
                                                  const int* __restrict__ rowptr,
                                                  const int* __restrict__ col,
                                                  const float* __restrict__ epss, int layer,
                                                  float* __restrict__ t, int n) {
    int wid = (blockIdx.x * 256 + threadIdx.x) >> 6;
    int lane = threadIdx.x & 63;
    if (wid >= n) return;
    float eps = epss[layer];
    int r0 = rowptr[wid], r1 = rowptr[wid + 1];
    float acc = (1.0f + eps) * h[(size_t)wid * 64 + lane];
    int i = r0;
    for (; i + 3 < r1; i += 4) {
        int c0 = col[i], c1 = col[i + 1], c2 = col[i + 2], c3 = col[i + 3];
        float a0 = h[(size_t)c0 * 64 + lane];
        float a1 = h[(size_t)c1 * 64 + lane];
        float a2 = h[(size_t)c2 * 64 + lane];
        float a3 = h[(size_t)c3 * 64 + lane];
        acc += (a0 + a1) + (a2 + a3);
    }
    for (; i < r1; ++i) acc += h[(size_t)col[i] * 64 + lane];
    t[(size_t)wid * 64 + lane] = acc;
}

// ---------------- fused 2-layer MLP + BN partial stats ----------------
// 128 nodes/block, thread-per-node. Weight rows are uniform loads -> SGPRs.
__global__ __launch_bounds__(128) void gin_mlp(const float* __restrict__ t_in,
                                               float* __restrict__ z_out,
                                               const float* __restrict__ W1g,
                                               const float* __restrict__ b1g,
                                               const float* __restrict__ W2g,
                                               const float* __restrict__ b2g,
                                               float* __restrict__ stats, int layer, int n) {
    __shared__ float tile[128 * 65];
    const float* __restrict__ W1 = W1g + layer * 4096;
    const float* __restrict__ W2 = W2g + layer * 4096;
    const float* __restrict__ b1 = b1g + layer * 64;
    const float* __restrict__ b2 = b2g + layer * 64;
    float* statS = stats + layer * 128;
    float* statQ = statS + 64;
    int tid = threadIdx.x;
    int base = blockIdx.x * 128;

    // stage 128 rows, coalesced
    {
        const float4* __restrict__ src = (const float4*)(t_in + (size_t)base * 64);
        #pragma unroll
        for (int it = 0; it < 16; ++it) {
            int idx4 = it * 128 + tid;
            int row = idx4 >> 4, c = (idx4 & 15) * 4;
            float4 v = make_float4(0.f, 0.f, 0.f, 0.f);
            if (base + row < n) v = src[idx4];
            float* d = &tile[row * 65 + c];
            d[0] = v.x; d[1] = v.y; d[2] = v.z; d[3] = v.w;
        }
    }
    __syncthreads();

    float acc[64];
    float* myrow = &tile[tid * 65];
    // z1 = relu(t @ W1 + b1)
    #pragma unroll
    for (int j = 0; j < 64; ++j) acc[j] = b1[j];
    for (int k = 0; k < 64; ++k) {
        float tk = myrow[k];
        const float* __restrict__ w = W1 + k * 64;
        #pragma unroll
        for (int j = 0; j < 64; ++j) acc[j] = fmaf(tk, w[j], acc[j]);
    }
    #pragma unroll
    for (int j = 0; j < 64; ++j) myrow[j] = fmaxf(acc[j], 0.f);
    // z2 = relu(z1 @ W2 + b2)
    #pragma unroll
    for (int j = 0; j < 64; ++j) acc[j] = b2[j];
    for (int k = 0; k < 64; ++k) {
        float tk = myrow[k];
        const float* __restrict__ w = W2 + k * 64;
        #pragma unroll
        for (int j = 0; j < 64; ++j) acc[j] = fmaf(tk, w[j], acc[j]);
    }
    #pragma unroll
    for (int j = 0; j < 64; ++j) myrow[j] = fmaxf(acc[j], 0.f);
    __syncthreads();

    // BN partial sums: wave w sums rows [w*64, w*64+64)
    {
        int lane = tid & 63, wv = tid >> 6;
        float s = 0.f, q = 0.f;
        for (int r = wv * 64; r < wv * 64 + 64; ++r) {
            if (base + r < n) {
                float v = tile[r * 65 + lane];
                s += v;
                q += v * v;
            }
        }
        atomicAdd(&statS[lane], s);
        atomicAdd(&statQ[lane], q);
    }

    // coalesced write-out
    {
        float4* __restrict__ dst4 = (float4*)(z_out + (size_t)base * 64);
        #pragma unroll
        for (int it = 0; it < 16; ++it) {
            int idx4 = it * 128 + tid;
            int row = idx4 >> 4, c = (idx4 & 15) * 4;
            if (base + row < n) {
                float* sp = &tile[row * 65 + c];
                dst4[idx4] = make_float4(sp[0], sp[1], sp[2], sp[3]);
            }
        }
    }
}

// ---------------- BN finalize: scale/shift per feature ----------------
__global__ void gin_bnfin(const float* __restrict__ stats, const float* __restrict__ gammas,
                          const float* __restrict__ betas, float* __restrict__ ss,
                          int layer, float n) {
    int f = threadIdx.x;  // 64
    float mu = stats[layer * 128 + f] / n;
    float var = stats[layer * 128 + 64 + f] / n - mu * mu;
    float rs = rsqrtf(var + 1e-5f);
    float g = gammas[layer * 64 + f];
    float b = betas[layer * 64 + f];
    ss[layer * 128 + f] = g * rs;
    ss[layer * 128 + 64 + f] = b - g * rs * mu;
}

// ---------------- normalize + relu ----------------
__global__ void gin_norm(const float* __restrict__ z, const float* __restrict__ ss,
                         float* __restrict__ h, int layer, int n4) {
    int i = blockIdx.x * blockDim.x + threadIdx.x;
    if (i >= n4) return;
    const float4* z4 = (const float4*)z;
    const float4* s4 = (const float4*)(ss + layer * 128);
    const float4* t4 = (const float4*)(ss + layer * 128 + 64);
    float4 v = z4[i];
    int f = i & 15;
    float4 sc = s4[f], sh = t4[f];
    float4 r;
    r.x = fmaxf(fmaf(v.x, sc.x, sh.x), 0.f);
    r.y = fmaxf(fmaf(v.y, sc.y, sh.y), 0.f);
    r.z = fmaxf(fmaf(v.z, sc.z, sh.z), 0.f);
    r.w = fmaxf(fmaf(v.w, sc.w, sh.w), 0.f);
    ((float4*)h)[i] = r;
}

// ---------------- final linear: out = h @ lin_w + lin_b ----------------
__global__ __launch_bounds__(128) void gin_lin(const float* __restrict__ h,
                                               const float* __restrict__ lw,
                                               const float* __restrict__ lb,
                                               float* __restrict__ out, int n) {
    __shared__ float tile[128 * 65];
    int tid = threadIdx.x;
    int base = blockIdx.x * 128;
    {
        const float4* __restrict__ src = (const float4*)(h + (size_t)base * 64);
        #pragma unroll
        for (int it = 0; it < 16; ++it) {
            int idx4 = it * 128 + tid;
            int row = idx4 >> 4, c = (idx4 & 15) * 4;
            float4 v = make_float4(0.f, 0.f, 0.f, 0.f);
            if (base + row < n) v = src[idx4];
            float* d = &tile[row * 65 + c];
            d[0] = v.x; d[1] = v.y; d[2] = v.z; d[3] = v.w;
        }
    }
    __syncthreads();
    float acc[32];
    float* myrow = &tile[tid * 65];
    #pragma unroll
    for (int j = 0; j < 32; ++j) acc[j] = lb[j];
    for (int k = 0; k < 64; ++k) {
        float tk = myrow[k];
        const float* __restrict__ w = lw + k * 32;
        #pragma unroll
        for (int j = 0; j < 32; ++j) acc[j] = fmaf(tk, w[j], acc[j]);
    }
    #pragma unroll
    for (int j = 0; j < 32; ++j) myrow[j] = acc[j];
    __syncthreads();
    {
        float4* __restrict__ dst4 = (float4*)(out + (size_t)base * 32);
        #pragma unroll
        for (int it = 0; it < 8; ++it) {
            int idx4 = it * 128 + tid;
            int row = idx4 >> 3, c = (idx4 & 7) * 4;
            if (base + row < n) {
                float* sp = &tile[row * 65 + c];
                dst4[idx4] = make_float4(sp[0], sp[1], sp[2], sp[3]);
            }
        }
    }
}

extern "C" void kernel_launch(void* const* d_in, const int* in_sizes, int n_in,
                              void* d_out, int out_size, void* d_ws, size_t ws_size,
                              hipStream_t stream) {
    const float* x      = (const float*)d_in[0];
    const void*  edge   = d_in[1];
    const float* W1s    = (const float*)d_in[2];
    const float* b1s    = (const float*)d_in[3];
    const float* W2s    = (const float*)d_in[4];
    const float* b2s    = (const float*)d_in[5];
    const float* gammas = (const float*)d_in[6];
    const float* betas  = (const float*)d_in[7];
    const float* epss   = (const float*)d_in[8];
    const float* lin_w  = (const float*)d_in[9];
    const float* lin_b  = (const float*)d_in[10];
    float* out = (float*)d_out;

    const int N = in_sizes[0] / 64;
    const int E = in_sizes[1] / 2;
    const int nc = (N + 255) / 256;  // scan chunks

    // workspace carve-up (256B aligned)
    char* w = (char*)d_ws;
    auto take = [&](size_t bytes) {
        char* p = w;
        w += (bytes + 255) & ~(size_t)255;
        return p;
    };
    float* A      = (float*)take((size_t)N * 64 * 4);  // t / z buffer
    float* B      = (float*)take((size_t)N * 64 * 4);  // h buffer
    int*   col    = (int*)take((size_t)E * 4);
    int*   rowptr = (int*)take((size_t)(N + 1) * 4);
    int*   cnt    = (int*)take((size_t)N * 4);         // also cursor
    int*   csum   = (int*)take((size_t)nc * 4);
    int*   coff   = (int*)take((size_t)nc * 4);
    float* stats  = (float*)take(3 * 128 * 4);
    float* ss     = (float*)take(3 * 128 * 4);
    int*   flag   = (int*)take(4);

    const int gE = (E + 255) / 256;
    const int gN = (N + 255) / 256;

    // CSR build
    gin_detect<<<1, 1, 0, stream>>>(edge, flag, E);
    hipMemsetAsync(cnt, 0, (size_t)N * 4, stream);
    hipMemsetAsync(stats, 0, 3 * 128 * 4, stream);
    gin_hist<<<gE, 256, 0, stream>>>(edge, flag, cnt, E);
    gin_scanA<<<nc, 256, 0, stream>>>(cnt, rowptr, csum, N);
    gin_scanB<<<1, 512, 0, stream>>>(csum, coff, nc);
    gin_scanC<<<gN, 256, 0, stream>>>(rowptr, coff, N, E);
    gin_copy<<<gN, 256, 0, stream>>>(rowptr, cnt, N);
    gin_fill<<<gE, 256, 0, stream>>>(edge, flag, cnt, col, E);

    const int gGather = (N + 3) / 4;       // 4 waves/block, wave per node
    const int gMlp    = (N + 127) / 128;
    const int gNorm   = (N * 16 + 255) / 256;

    for (int L = 0; L < 3; ++L) {
        const float* hin = (L == 0) ? x : B;
        gin_gather<<<gGather, 256, 0, stream>>>(hin, rowptr, col, epss, L, A, N);
        gin_mlp<<<gMlp, 128, 0, stream>>>(A, A, W1s, b1s, W2s, b2s, stats, L, N);
        gin_bnfin<<<1, 64, 0, stream>>>(stats, gammas, betas, ss, L, (float)N);
        gin_norm<<<gNorm, 256, 0, stream>>>(A, ss, B, L, N * 16);
    }
    gin_lin<<<gMlp, 128, 0, stream>>>(B, lin_w, lin_b, out, N);
}

// Round 3
// 584.896 us; speedup vs baseline: 1.2205x; 1.2205x over previous
//
#include <hip/hip_runtime.h>

// ---------------- edge dtype detection ----------------
__global__ void gin_detect(const void* __restrict__ edge, int* __restrict__ flag, int E) {
    const int* p = (const int*)edge;
    int is64 = 1;
    int m = (E < 64) ? E : 64;
    for (int i = 0; i < m; ++i)
        if (p[2 * i + 1] != 0) is64 = 0;
    *flag = is64;
}

__device__ __forceinline__ void load_edge(const void* edge, int is64, int E, int e,
                                          int& s, int& d) {
    if (is64) {
        const long long* p = (const long long*)edge;
        s = (int)p[e];
        d = (int)p[E + e];
    } else {
        const int* p = (const int*)edge;
        s = p[e];
        d = p[E + e];
    }
}

// ---------------- CSR build ----------------
__global__ void gin_hist(const void* __restrict__ edge, const int* __restrict__ flag,
                         int* __restrict__ cnt, int E) {
    int e = blockIdx.x * blockDim.x + threadIdx.x;
    if (e >= E) return;
    int is64 = *flag;
    int s, d;
    load_edge(edge, is64, E, e, s, d);
    atomicAdd(&cnt[d], 1);
}

__global__ __launch_bounds__(256) void gin_scanA(const int* __restrict__ cnt,
                                                 int* __restrict__ rowptr,
                                                 int* __restrict__ chunksum, int n) {
    int tid = threadIdx.x;
    int gid = blockIdx.x * 256 + tid;
    int v = (gid < n) ? cnt[gid] : 0;
    int lane = tid & 63, wv = tid >> 6;
    int x = v;
    #pragma unroll
    for (int d = 1; d < 64; d <<= 1) {
        int y = __shfl_up(x, d, 64);
        if (lane >= d) x += y;
    }
    __shared__ int wsum[4];
    __shared__ int woff[4];
    if (lane == 63) wsum[wv] = x;
    __syncthreads();
    if (tid == 0) {
        int a = 0;
        #pragma unroll
        for (int i = 0; i < 4; ++i) { woff[i] = a; a += wsum[i]; }
        chunksum[blockIdx.x] = a;
    }
    __syncthreads();
    if (gid < n) rowptr[gid] = x - v + woff[wv];
}

__global__ __launch_bounds__(512) void gin_scanB(const int* __restrict__ s,
                                                 int* __restrict__ off, int nc) {
    int tid = threadIdx.x;
    int v = (tid < nc) ? s[tid] : 0;
    int lane = tid & 63, wv = tid >> 6;
    int x = v;
    #pragma unroll
    for (int d = 1; d < 64; d <<= 1) {
        int y = __shfl_up(x, d, 64);
        if (lane >= d) x += y;
    }
    __shared__ int wsum[8];
    __shared__ int woff[8];
    if (lane == 63) wsum[wv] = x;
    __syncthreads();
    if (tid == 0) {
        int a = 0;
        #pragma unroll
        for (int i = 0; i < 8; ++i) { woff[i] = a; a += wsum[i]; }
    }
    __syncthreads();
    if (tid < nc) off[tid] = x - v + woff[wv];
}

__global__ void gin_scanC(int* __restrict__ rowptr, const int* __restrict__ off,
                          int n, int E) {
    int gid = blockIdx.x * blockDim.x + threadIdx.x;
    if (gid < n) rowptr[gid] += off[gid >> 8];
    if (gid == 0) rowptr[n] = E;
}

__global__ void gin_copy(const int* __restrict__ r, int* __restrict__ c, int n) {
    int gid = blockIdx.x * blockDim.x + threadIdx.x;
    if (gid < n) c[gid] = r[gid];
}

__global__ void gin_fill(const void* __restrict__ edge, const int* __restrict__ flag,
                         int* __restrict__ cursor, int* __restrict__ col, int E) {
    int e = blockIdx.x * blockDim.x + threadIdx.x;
    if (e >= E) return;
    int is64 = *flag;
    int s, d;
    load_edge(edge, is64, E, e, s, d);
    int pos = atomicAdd(&cursor[d], 1);
    col[pos] = s;
}

// ---------------- gather with fused BN+relu on input ----------------
// t[n] = (1+eps)*f(z[n]) + sum_j f(z[j]),  f = apply? relu(z*sc+sh) : z
// one wave per node, lane = feature (coalesced 256B per neighbor)
__global__ __launch_bounds__(256) void gin_gather(const float* __restrict__ z,
                                                  const int* __restrict__ rowptr,
                                                  const int* __restrict__ col,
                                                  const float* __restrict__ epss,
                                                  const float* __restrict__ ss,
                                                  int layer, int apply,
                                                  float* __restrict__ t, int n) {
    int wid = (blockIdx.x * 256 + threadIdx.x) >> 6;
    int lane = threadIdx.x & 63;
    if (wid >= n) return;
    float eps = epss[layer];
    float sc = 1.f, sh = 0.f;
    if (apply) {
        sc = ss[(layer - 1) * 128 + lane];
        sh = ss[(layer - 1) * 128 + 64 + lane];
    }
    int r0 = rowptr[wid], r1 = rowptr[wid + 1];
    float v0 = z[(size_t)wid * 64 + lane];
    if (apply) v0 = fmaxf(fmaf(v0, sc, sh), 0.f);
    float acc = (1.0f + eps) * v0;
    int i = r0;
    if (apply) {
        for (; i + 3 < r1; i += 4) {
            int c0 = col[i], c1 = col[i + 1], c2 = col[i + 2], c3 = col[i + 3];
            float a0 = z[(size_t)c0 * 64 + lane];
            float a1 = z[(size_t)c1 * 64 + lane];
            float a2 = z[(size_t)c2 * 64 + lane];
            float a3 = z[(size_t)c3 * 64 + lane];
            a0 = fmaxf(fmaf(a0, sc, sh), 0.f);
            a1 = fmaxf(fmaf(a1, sc, sh), 0.f);
            a2 = fmaxf(fmaf(a2, sc, sh), 0.f);
            a3 = fmaxf(fmaf(a3, sc, sh), 0.f);
            acc += (a0 + a1) + (a2 + a3);
        }
        for (; i < r1; ++i) {
            float a = z[(size_t)col[i] * 64 + lane];
            acc += fmaxf(fmaf(a, sc, sh), 0.f);
        }
    } else {
        for (; i + 3 < r1; i += 4) {
            int c0 = col[i], c1 = col[i + 1], c2 = col[i + 2], c3 = col[i + 3];
            float a0 = z[(size_t)c0 * 64 + lane];
            float a1 = z[(size_t)c1 * 64 + lane];
            float a2 = z[(size_t)c2 * 64 + lane];
            float a3 = z[(size_t)c3 * 64 + lane];
            acc += (a0 + a1) + (a2 + a3);
        }
        for (; i < r1; ++i) acc += z[(size_t)col[i] * 64 + lane];
    }
    t[(size_t)wid * 64 + lane] = acc;
}

// ---------------- fused 2-layer MLP + BN partial stats ----------------
// Register-tiled GEMM: 256 threads, 128 nodes/block.
// Thread (tx=tid&15, ty=tid>>4) computes rows {ty+16r} x cols {4tx..4tx+3}.
// A from LDS (tx-uniform broadcast scalar reads, conflict-free by row striping),
// W from global dwordx4 (L1-resident, 4-lane broadcast, pipelined over k).
__global__ __launch_bounds__(256) void gin_mlp(const float* __restrict__ t_in,
                                               float* __restrict__ z_out,
                                               const float* __restrict__ W1g,
                                               const float* __restrict__ b1g,
                                               const float* __restrict__ W2g,
                                               const float* __restrict__ b2g,
                                               float* __restrict__ stats, int layer, int n) {
    __shared__ float Z[128 * 68];
    __shared__ float sS[64], sQ[64];
    const float* __restrict__ W1 = W1g + layer * 4096;
    const float* __restrict__ W2 = W2g + layer * 4096;
    int tid = threadIdx.x;
    int base = blockIdx.x * 128;

    // stage 128x64 rows, coalesced float4
    {
        const float4* __restrict__ src = (const float4*)(t_in + (size_t)base * 64);
        #pragma unroll
        for (int it = 0; it < 8; ++it) {
            int idx4 = it * 256 + tid;
            int row = idx4 >> 4, c = (idx4 & 15) * 4;
            float4 v = make_float4(0.f, 0.f, 0.f, 0.f);
            if (base + row < n) v = src[idx4];
            *(float4*)&Z[row * 68 + c] = v;
        }
    }
    if (tid < 64) { sS[tid] = 0.f; sQ[tid] = 0.f; }
    __syncthreads();

    int tx = tid & 15, ty = tid >> 4;
    float acc[8][4];

    // ---- mm1: z1 = relu(t @ W1 + b1) ----
    {
        float4 b = *(const float4*)(b1g + layer * 64 + 4 * tx);
        #pragma unroll
        for (int r = 0; r < 8; ++r) {
            acc[r][0] = b.x; acc[r][1] = b.y; acc[r][2] = b.z; acc[r][3] = b.w;
        }
    }
    #pragma unroll 4
    for (int k = 0; k < 64; ++k) {
        float4 w = *(const float4*)(W1 + k * 64 + 4 * tx);
        #pragma unroll
        for (int r = 0; r < 8; ++r) {
            float a = Z[(ty + 16 * r) * 68 + k];
            acc[r][0] = fmaf(a, w.x, acc[r][0]);
            acc[r][1] = fmaf(a, w.y, acc[r][1]);
            acc[r][2] = fmaf(a, w.z, acc[r][2]);
            acc[r][3] = fmaf(a, w.w, acc[r][3]);
        }
    }
    __syncthreads();
    #pragma unroll
    for (int r = 0; r < 8; ++r) {
        float4 v;
        v.x = fmaxf(acc[r][0], 0.f);
        v.y = fmaxf(acc[r][1], 0.f);
        v.z = fmaxf(acc[r][2], 0.f);
        v.w = fmaxf(acc[r][3], 0.f);
        *(float4*)&Z[(ty + 16 * r) * 68 + 4 * tx] = v;
    }
    __syncthreads();

    // ---- mm2: z2 = relu(z1 @ W2 + b2) ----
    {
        float4 b = *(const float4*)(b2g + layer * 64 + 4 * tx);
        #pragma unroll
        for (int r = 0; r < 8; ++r) {
            acc[r][0] = b.x; acc[r][1] = b.y; acc[r][2] = b.z; acc[r][3] = b.w;
        }
    }
    #pragma unroll 4
    for (int k = 0; k < 64; ++k) {
        float4 w = *(const float4*)(W2 + k * 64 + 4 * tx);
        #pragma unroll
        for (int r = 0; r < 8; ++r) {
            float a = Z[(ty + 16 * r) * 68 + k];
            acc[r][0] = fmaf(a, w.x, acc[r][0]);
            acc[r][1] = fmaf(a, w.y, acc[r][1]);
            acc[r][2] = fmaf(a, w.z, acc[r][2]);
            acc[r][3] = fmaf(a, w.w, acc[r][3]);
        }
    }
    #pragma unroll
    for (int r = 0; r < 8; ++r) {
        acc[r][0] = fmaxf(acc[r][0], 0.f);
        acc[r][1] = fmaxf(acc[r][1], 0.f);
        acc[r][2] = fmaxf(acc[r][2], 0.f);
        acc[r][3] = fmaxf(acc[r][3], 0.f);
    }

    // ---- BN partial stats (mask padded rows) ----
    {
        float s0 = 0.f, s1 = 0.f, s2 = 0.f, s3 = 0.f;
        float q0 = 0.f, q1 = 0.f, q2 = 0.f, q3 = 0.f;
        #pragma unroll
        for (int r = 0; r < 8; ++r) {
            if (base + ty + 16 * r < n) {
                s0 += acc[r][0]; q0 += acc[r][0] * acc[r][0];
                s1 += acc[r][1]; q1 += acc[r][1] * acc[r][1];
                s2 += acc[r][2]; q2 += acc[r][2] * acc[r][2];
                s3 += acc[r][3]; q3 += acc[r][3] * acc[r][3];
            }
        }
        atomicAdd(&sS[4 * tx + 0], s0); atomicAdd(&sQ[4 * tx + 0], q0);
        atomicAdd(&sS[4 * tx + 1], s1); atomicAdd(&sQ[4 * tx + 1], q1);
        atomicAdd(&sS[4 * tx + 2], s2); atomicAdd(&sQ[4 * tx + 2], q2);
        atomicAdd(&sS[4 * tx + 3], s3); atomicAdd(&sQ[4 * tx + 3], q3);
    }

    // ---- write z2, coalesced float4 ----
    #pragma unroll
    for (int r = 0; r < 8; ++r) {
        int row = base + ty + 16 * r;
        if (row < n) {
            float4 v;
            v.x = acc[r][0]; v.y = acc[r][1]; v.z = acc[r][2]; v.w = acc[r][3];
            *(float4*)(z_out + (size_t)row * 64 + 4 * tx) = v;
        }
    }
    __syncthreads();
    if (tid < 64) {
        atomicAdd(&stats[layer * 128 + tid], sS[tid]);
        atomicAdd(&stats[layer * 128 + 64 + tid], sQ[tid]);
    }
}

// ---------------- BN finalize: scale/shift per feature ----------------
__global__ void gin_bnfin(const float* __restrict__ stats, const float* __restrict__ gammas,
                          const float* __restrict__ betas, float* __restrict__ ss,
                          int layer, float n) {
    int f = threadIdx.x;  // 64
    float mu = stats[layer * 128 + f] / n;
    float var = stats[layer * 128 + 64 + f] / n - mu * mu;
    float rs = rsqrtf(var + 1e-5f);
    float g = gammas[layer * 64 + f];
    float b = betas[layer * 64 + f];
    ss[layer * 128 + f] = g * rs;
    ss[layer * 128 + 64 + f] = b - g * rs * mu;
}

// ---------------- final linear with fused BN+relu on input ----------------
// out = relu(bn(z2_layer2)) @ lin_w + lin_b.  Register-tiled 4x4.
__global__ __launch_bounds__(256) void gin_lin(const float* __restrict__ zin,
                                               const float* __restrict__ ss,
                                               const float* __restrict__ lw,
                                               const float* __restrict__ lb,
                                               float* __restrict__ out, int n) {
    __shared__ float Z[128 * 68];
    int tid = threadIdx.x;
    int base = blockIdx.x * 128;
    // stage with fused f = relu(z*sc+sh), ss of layer 2
    {
        const float4* __restrict__ src = (const float4*)(zin + (size_t)base * 64);
        #pragma unroll
        for (int it = 0; it < 8; ++it) {
            int idx4 = it * 256 + tid;
            int row = idx4 >> 4, c = (idx4 & 15) * 4;
            float4 v = make_float4(0.f, 0.f, 0.f, 0.f);
            if (base + row < n) v = src[idx4];
            float4 sc = *(const float4*)(ss + 256 + c);
            float4 sh = *(const float4*)(ss + 256 + 64 + c);
            float4 r;
            r.x = fmaxf(fmaf(v.x, sc.x, sh.x), 0.f);
            r.y = fmaxf(fmaf(v.y, sc.y, sh.y), 0.f);
            r.z = fmaxf(fmaf(v.z, sc.z, sh.z), 0.f);
            r.w = fmaxf(fmaf(v.w, sc.w, sh.w), 0.f);
            *(float4*)&Z[row * 68 + c] = r;
        }
    }
    __syncthreads();
    int tx = tid & 7, ty = tid >> 3;  // 8 x 32
    float acc[4][4];
    {
        float4 b = *(const float4*)(lb + 4 * tx);
        #pragma unroll
        for (int r = 0; r < 4; ++r) {
            acc[r][0] = b.x; acc[r][1] = b.y; acc[r][2] = b.z; acc[r][3] = b.w;
        }
    }
    #pragma unroll 4
    for (int k = 0; k < 64; ++k) {
        float4 w = *(const float4*)(lw + k * 32 + 4 * tx);
        #pragma unroll
        for (int r = 0; r < 4; ++r) {
            float a = Z[(ty + 32 * r) * 68 + k];
            acc[r][0] = fmaf(a, w.x, acc[r][0]);
            acc[r][1] = fmaf(a, w.y, acc[r][1]);
            acc[r][2] = fmaf(a, w.z, acc[r][2]);
            acc[r][3] = fmaf(a, w.w, acc[r][3]);
        }
    }
    #pragma unroll
    for (int r = 0; r < 4; ++r) {
        int row = base + ty + 32 * r;
        if (row < n) {
            float4 v;
            v.x = acc[r][0]; v.y = acc[r][1]; v.z = acc[r][2]; v.w = acc[r][3];
            *(float4*)(out + (size_t)row * 32 + 4 * tx) = v;
        }
    }
}

extern "C" void kernel_launch(void* const* d_in, const int* in_sizes, int n_in,
                              void* d_out, int out_size, void* d_ws, size_t ws_size,
                              hipStream_t stream) {
    const float* x      = (const float*)d_in[0];
    const void*  edge   = d_in[1];
    const float* W1s    = (const float*)d_in[2];
    const float* b1s    = (const float*)d_in[3];
    const float* W2s    = (const float*)d_in[4];
    const float* b2s    = (const float*)d_in[5];
    const float* gammas = (const float*)d_in[6];
    const float* betas  = (const float*)d_in[7];
    const float* epss   = (const float*)d_in[8];
    const float* lin_w  = (const float*)d_in[9];
    const float* lin_b  = (const float*)d_in[10];
    float* out = (float*)d_out;

    const int N = in_sizes[0] / 64;
    const int E = in_sizes[1] / 2;
    const int nc = (N + 255) / 256;

    char* w = (char*)d_ws;
    auto take = [&](size_t bytes) {
        char* p = w;
        w += (bytes + 255) & ~(size_t)255;
        return p;
    };
    float* A      = (float*)take((size_t)N * 64 * 4);  // gather output t
    float* B      = (float*)take((size_t)N * 64 * 4);  // z2 buffer
    int*   col    = (int*)take((size_t)E * 4);
    int*   rowptr = (int*)take((size_t)(N + 1) * 4);
    int*   cnt    = (int*)take((size_t)N * 4);         // also cursor
    int*   csum   = (int*)take((size_t)nc * 4);
    int*   coff   = (int*)take((size_t)nc * 4);
    float* stats  = (float*)take(3 * 128 * 4);
    float* ss     = (float*)take(3 * 128 * 4);
    int*   flag   = (int*)take(4);

    const int gE = (E + 255) / 256;
    const int gN = (N + 255) / 256;

    gin_detect<<<1, 1, 0, stream>>>(edge, flag, E);
    hipMemsetAsync(cnt, 0, (size_t)N * 4, stream);
    hipMemsetAsync(stats, 0, 3 * 128 * 4, stream);
    gin_hist<<<gE, 256, 0, stream>>>(edge, flag, cnt, E);
    gin_scanA<<<nc, 256, 0, stream>>>(cnt, rowptr, csum, N);
    gin_scanB<<<1, 512, 0, stream>>>(csum, coff, nc);
    gin_scanC<<<gN, 256, 0, stream>>>(rowptr, coff, N, E);
    gin_copy<<<gN, 256, 0, stream>>>(rowptr, cnt, N);
    gin_fill<<<gE, 256, 0, stream>>>(edge, flag, cnt, col, E);

    const int gGather = (N + 3) / 4;     // wave per node
    const int gMlp    = (N + 127) / 128;

    for (int L = 0; L < 3; ++L) {
        const float* zin = (L == 0) ? x : B;
        gin_gather<<<gGather, 256, 0, stream>>>(zin, rowptr, col, epss, ss, L, (L > 0) ? 1 : 0, A, N);
        gin_mlp<<<gMlp, 256, 0, stream>>>(A, B, W1s, b1s, W2s, b2s, stats, L, N);
        gin_bnfin<<<1, 64, 0, stream>>>(stats, gammas, betas, ss, L, (float)N);
    }
    gin_lin<<<gMlp, 256, 0, stream>>>(B, ss, lin_w, lin_b, out, N);
}

// Round 5
// 477.893 us; speedup vs baseline: 1.4938x; 1.2239x over previous
//
#include <hip/hip_runtime.h>

#define NBMAX 256   // coarse buckets (N/512), must be <= 256
#define CHB   7168  // edges per binning block (LDS-limited)

__device__ __forceinline__ unsigned short f2bf(float f) {
    unsigned u = __float_as_uint(f);
    unsigned r = (u + 0x7FFF + ((u >> 16) & 1)) >> 16;  // RNE
    return (unsigned short)r;
}
__device__ __forceinline__ float bf2f(unsigned short u) {
    return __uint_as_float(((unsigned)u) << 16);
}

// exclusive scan of v over 256 threads (4 waves); all threads must call
__device__ __forceinline__ int scan256(int v, int* wsum, int* woff) {
    int t = threadIdx.x, lane = t & 63, wv = t >> 6;
    int x = v;
    #pragma unroll
    for (int d = 1; d < 64; d <<= 1) {
        int y = __shfl_up(x, d, 64);
        if (lane >= d) x += y;
    }
    if (lane == 63) wsum[wv] = x;
    __syncthreads();
    if (t == 0) {
        int a = 0;
        #pragma unroll
        for (int i = 0; i < 4; ++i) { woff[i] = a; a += wsum[i]; }
    }
    __syncthreads();
    return x - v + woff[wv];
}

// ---------------- edge dtype detection ----------------
__global__ void gin_detect(const void* __restrict__ edge, int* __restrict__ flag, int E) {
    const int* p = (const int*)edge;
    int is64 = 1;
    int m = (E < 64) ? E : 64;
    for (int i = 0; i < m; ++i)
        if (p[2 * i + 1] != 0) is64 = 0;
    *flag = is64;
}

// ---------------- x -> bf16 ----------------
__global__ __launch_bounds__(256) void gin_x16(const float* __restrict__ x,
                                               unsigned short* __restrict__ o, int n16) {
    int i = blockIdx.x * 256 + threadIdx.x;  // one float4 group
    if (i >= n16) return;
    float4 v = ((const float4*)x)[i];
    ushort4 u;
    u.x = f2bf(v.x); u.y = f2bf(v.y); u.z = f2bf(v.z); u.w = f2bf(v.w);
    ((ushort4*)o)[i] = u;
}

// ---------------- coarse histogram over dst>>9 ----------------
__global__ __launch_bounds__(256) void gin_cbhist(const void* __restrict__ edge,
                                                  const int* __restrict__ flag,
                                                  int* __restrict__ cbcnt, int E, int nb) {
    __shared__ int lc[NBMAX];
    int t = threadIdx.x;
    if (t < nb) lc[t] = 0;
    __syncthreads();
    int is64 = *flag;
    int stride = gridDim.x * 256;
    for (int e = blockIdx.x * 256 + t; e < E; e += stride) {
        int d = is64 ? (int)((const long long*)edge)[E + e] : ((const int*)edge)[E + e];
        atomicAdd(&lc[d >> 9], 1);
    }
    __syncthreads();
    if (t < nb && lc[t]) atomicAdd(&cbcnt[t], lc[t]);
}

// ---------------- coarse scan -> bucket bases + cursors ----------------
__global__ __launch_bounds__(256) void gin_cbscan(const int* __restrict__ cbcnt,
                                                  int* __restrict__ cbbase,
                                                  int* __restrict__ cbcursor, int nb,
                                                  int* __restrict__ rowptr, int n, int E) {
    __shared__ int wsum[4], woff[4];
    int t = threadIdx.x;
    int v = (t < nb) ? cbcnt[t] : 0;
    int excl = scan256(v, wsum, woff);
    if (t < nb) { cbbase[t] = excl; cbcursor[t] = excl; }
    if (t == nb - 1) cbbase[nb] = excl + v;
    if (t == 0) rowptr[n] = E;
}

// ---------------- bin edges into coarse buckets (LDS-staged, coalesced flush) ----
__global__ __launch_bounds__(256) void gin_binscatter(const void* __restrict__ edge,
                                                      const int* __restrict__ flag,
                                                      int* __restrict__ cbcursor,
                                                      uint2* __restrict__ ebuf, int E, int nb) {
    __shared__ int cnt[NBMAX];
    __shared__ int dlt[NBMAX];
    __shared__ int cur[NBMAX];
    __shared__ int wsum[4], woff[4];
    __shared__ uint2 buf[CHB];
    int t = threadIdx.x;
    int beg = blockIdx.x * CHB;
    int m = E - beg; if (m > CHB) m = CHB;
    if (t < nb) cnt[t] = 0;
    __syncthreads();
    int is64 = *flag;
    for (int j = t; j < m; j += 256) {
        int e = beg + j;
        int d = is64 ? (int)((const long long*)edge)[E + e] : ((const int*)edge)[E + e];
        atomicAdd(&cnt[d >> 9], 1);
    }
    __syncthreads();
    int v = (t < nb) ? cnt[t] : 0;
    int excl = scan256(v, wsum, woff);
    if (t < nb) {
        int gb = v ? atomicAdd(&cbcursor[t], v) : 0;
        dlt[t] = gb - excl;
        cur[t] = excl;
    }
    __syncthreads();
    for (int j = t; j < m; j += 256) {
        int e = beg + j;
        int s, d;
        if (is64) {
            s = (int)((const long long*)edge)[e];
            d = (int)((const long long*)edge)[E + e];
        } else {
            s = ((const int*)edge)[e];
            d = ((const int*)edge)[E + e];
        }
        int p = atomicAdd(&cur[d >> 9], 1);
        buf[p] = make_uint2((unsigned)s, (unsigned)d);
    }
    __syncthreads();
    for (int j = t; j < m; j += 256) {
        uint2 ed = buf[j];
        ebuf[j + dlt[(int)(ed.y >> 9)]] = ed;  // ~300B contiguous runs per bucket
    }
}

// ---------------- per-bucket CSR build (512 nodes/block) ----------------
__global__ __launch_bounds__(256) void gin_build(const uint2* __restrict__ ebuf,
                                                 const int* __restrict__ cbbase,
                                                 int* __restrict__ rowptr,
                                                 int* __restrict__ col, int n) {
    __shared__ int cnt[512];
    __shared__ int off[512];
    __shared__ int wsum[4], woff[4];
    int b = blockIdx.x, t = threadIdx.x;
    int beg = cbbase[b], end = cbbase[b + 1];
    cnt[t] = 0; cnt[t + 256] = 0;
    __syncthreads();
    for (int j = beg + t; j < end; j += 256)
        atomicAdd(&cnt[(int)(ebuf[j].y & 511)], 1);
    __syncthreads();
    int v0 = cnt[2 * t], v1 = cnt[2 * t + 1];
    int ep = scan256(v0 + v1, wsum, woff);
    off[2 * t] = ep;
    off[2 * t + 1] = ep + v0;
    __syncthreads();
    int node0 = b * 512 + 2 * t;
    if (node0 < n) rowptr[node0] = beg + off[2 * t];
    if (node0 + 1 < n) rowptr[node0 + 1] = beg + off[2 * t + 1];
    __syncthreads();
    // scatter src into bucket-local region (L2-absorbed), off reused as cursor
    for (int j = beg + t; j < end; j += 256) {
        uint2 ed = ebuf[j];
        int p = atomicAdd(&off[(int)(ed.y & 511)], 1);
        col[beg + p] = (int)ed.x;
    }
}

// ---------------- gather (bf16 rows): t[n] = (1+eps)*f(z[n]) + sum f(z[j]) ------
// wave per node; lane (g=lane>>4, q=lane&15) loads 4 features of strided nbrs
__global__ __launch_bounds__(256) void gin_gather(const unsigned short* __restrict__ zb,
                                                  const int* __restrict__ rowptr,
                                                  const int* __restrict__ col,
                                                  const float* __restrict__ epss,
                                                  const float* __restrict__ ss,
                                                  int layer, int apply,
                                                  float* __restrict__ t, int n) {
    int wid = (blockIdx.x * 256 + threadIdx.x) >> 6;
    int lane = threadIdx.x & 63;
    if (wid >= n) return;
    int g = lane >> 4, q = lane & 15;
    float4 sc = make_float4(1.f, 1.f, 1.f, 1.f);
    float4 sh = make_float4(0.f, 0.f, 0.f, 0.f);
    if (apply) {
        sc = *(const float4*)(ss + (layer - 1) * 128 + 4 * q);
        sh = *(const float4*)(ss + (layer - 1) * 128 + 64 + 4 * q);
    }
    int r0 = rowptr[wid], r1 = rowptr[wid + 1];
    float a0 = 0.f, a1 = 0.f, a2 = 0.f, a3 = 0.f;
    if (apply) {
        for (int base = r0; base < r1; base += 16) {
            int n0 = base + g, n1 = n0 + 4, n2 = n0 + 8, n3 = n0 + 12;
            ushort4 u0, u1, u2, u3;
            bool p0 = n0 < r1, p1 = n1 < r1, p2 = n2 < r1, p3 = n3 < r1;
            if (p0) u0 = *(const ushort4*)(zb + (size_t)col[n0] * 64 + 4 * q);
            if (p1) u1 = *(const ushort4*)(zb + (size_t)col[n1] * 64 + 4 * q);
            if (p2) u2 = *(const ushort4*)(zb + (size_t)col[n2] * 64 + 4 * q);
            if (p3) u3 = *(const ushort4*)(zb + (size_t)col[n3] * 64 + 4 * q);
            if (p0) {
                a0 += fmaxf(fmaf(bf2f(u0.x), sc.x, sh.x), 0.f);
                a1 += fmaxf(fmaf(bf2f(u0.y), sc.y, sh.y), 0.f);
                a2 += fmaxf(fmaf(bf2f(u0.z), sc.z, sh.z), 0.f);
                a3 += fmaxf(fmaf(bf2f(u0.w), sc.w, sh.w), 0.f);
            }
            if (p1) {
                a0 += fmaxf(fmaf(bf2f(u1.x), sc.x, sh.x), 0.f);
                a1 += fmaxf(fmaf(bf2f(u1.y), sc.y, sh.y), 0.f);
                a2 += fmaxf(fmaf(bf2f(u1.z), sc.z, sh.z), 0.f);
                a3 += fmaxf(fmaf(bf2f(u1.w), sc.w, sh.w), 0.f);
            }
            if (p2) {
                a0 += fmaxf(fmaf(bf2f(u2.x), sc.x, sh.x), 0.f);
                a1 += fmaxf(fmaf(bf2f(u2.y), sc.y, sh.y), 0.f);
                a2 += fmaxf(fmaf(bf2f(u2.z), sc.z, sh.z), 0.f);
                a3 += fmaxf(fmaf(bf2f(u2.w), sc.w, sh.w), 0.f);
            }
            if (p3) {
                a0 += fmaxf(fmaf(bf2f(u3.x), sc.x, sh.x), 0.f);
                a1 += fmaxf(fmaf(bf2f(u3.y), sc.y, sh.y), 0.f);
                a2 += fmaxf(fmaf(bf2f(u3.z), sc.z, sh.z), 0.f);
                a3 += fmaxf(fmaf(bf2f(u3.w), sc.w, sh.w), 0.f);
            }
        }
    } else {
        for (int base = r0; base < r1; base += 16) {
            int n0 = base + g, n1 = n0 + 4, n2 = n0 + 8, n3 = n0 + 12;
            ushort4 u0, u1, u2, u3;
            bool p0 = n0 < r1, p1 = n1 < r1, p2 = n2 < r1, p3 = n3 < r1;
            if (p0) u0 = *(const ushort4*)(zb + (size_t)col[n0] * 64 + 4 * q);
            if (p1) u1 = *(const ushort4*)(zb + (size_t)col[n1] * 64 + 4 * q);
            if (p2) u2 = *(const ushort4*)(zb + (size_t)col[n2] * 64 + 4 * q);
            if (p3) u3 = *(const ushort4*)(zb + (size_t)col[n3] * 64 + 4 * q);
            if (p0) { a0 += bf2f(u0.x); a1 += bf2f(u0.y); a2 += bf2f(u0.z); a3 += bf2f(u0.w); }
            if (p1) { a0 += bf2f(u1.x); a1 += bf2f(u1.y); a2 += bf2f(u1.z); a3 += bf2f(u1.w); }
            if (p2) { a0 += bf2f(u2.x); a1 += bf2f(u2.y); a2 += bf2f(u2.z); a3 += bf2f(u2.w); }
            if (p3) { a0 += bf2f(u3.x); a1 += bf2f(u3.y); a2 += bf2f(u3.z); a3 += bf2f(u3.w); }
        }
    }
    // reduce over the 4 neighbor slots
    a0 += __shfl_xor(a0, 16); a0 += __shfl_xor(a0, 32);
    a1 += __shfl_xor(a1, 16); a1 += __shfl_xor(a1, 32);
    a2 += __shfl_xor(a2, 16); a2 += __shfl_xor(a2, 32);
    a3 += __shfl_xor(a3, 16); a3 += __shfl_xor(a3, 32);
    if (g == 0) {
        float e1 = 1.f + epss[layer];
        ushort4 u = *(const ushort4*)(zb + (size_t)wid * 64 + 4 * q);
        float s0 = bf2f(u.x), s1 = bf2f(u.y), s2 = bf2f(u.z), s3 = bf2f(u.w);
        if (apply) {
            s0 = fmaxf(fmaf(s0, sc.x, sh.x), 0.f);
            s1 = fmaxf(fmaf(s1, sc.y, sh.y), 0.f);
            s2 = fmaxf(fmaf(s2, sc.z, sh.z), 0.f);
            s3 = fmaxf(fmaf(s3, sc.w, sh.w), 0.f);
        }
        a0 = fmaf(e1, s0, a0); a1 = fmaf(e1, s1, a1);
        a2 = fmaf(e1, s2, a2); a3 = fmaf(e1, s3, a3);
        *(float4*)(t + (size_t)wid * 64 + 4 * q) = make_float4(a0, a1, a2, a3);
    }
}

// ---------------- fused 2-layer MLP + BN partial stats (bf16 out) ----------------
__global__ __launch_bounds__(256) void gin_mlp(const float* __restrict__ t_in,
                                               unsigned short* __restrict__ z16,
                                               const float* __restrict__ W1g,
                                               const float* __restrict__ b1g,
                                               const float* __restrict__ W2g,
                                               const float* __restrict__ b2g,
                                               float* __restrict__ stats, int layer, int n) {
    __shared__ float Z[128 * 68];
    __shared__ float sS[64], sQ[64];
    const float* __restrict__ W1 = W1g + layer * 4096;
    const float* __restrict__ W2 = W2g + layer * 4096;
    int tid = threadIdx.x;
    int base = blockIdx.x * 128;

    {
        const float4* __restrict__ src = (const float4*)(t_in + (size_t)base * 64);
        #pragma unroll
        for (int it = 0; it < 8; ++it) {
            int idx4 = it * 256 + tid;
            int row = idx4 >> 4, c = (idx4 & 15) * 4;
            float4 v = make_float4(0.f, 0.f, 0.f, 0.f);
            if (base + row < n) v = src[idx4];
            *(float4*)&Z[row * 68 + c] = v;
        }
    }
    if (tid < 64) { sS[tid] = 0.f; sQ[tid] = 0.f; }
    __syncthreads();

    int tx = tid & 15, ty = tid >> 4;
    float acc[8][4];

    {
        float4 b = *(const float4*)(b1g + layer * 64 + 4 * tx);
        #pragma unroll
        for (int r = 0; r < 8; ++r) {
            acc[r][0] = b.x; acc[r][1] = b.y; acc[r][2] = b.z; acc[r][3] = b.w;
        }
    }
    #pragma unroll 4
    for (int k = 0; k < 64; ++k) {
        float4 w = *(const float4*)(W1 + k * 64 + 4 * tx);
        #pragma unroll
        for (int r = 0; r < 8; ++r) {
            float a = Z[(ty + 16 * r) * 68 + k];
            acc[r][0] = fmaf(a, w.x, acc[r][0]);
            acc[r][1] = fmaf(a, w.y, acc[r][1]);
            acc[r][2] = fmaf(a, w.z, acc[r][2]);
            acc[r][3] = fmaf(a, w.w, acc[r][3]);
        }
    }
    __syncthreads();
    #pragma unroll
    for (int r = 0; r < 8; ++r) {
        float4 v;
        v.x = fmaxf(acc[r][0], 0.f);
        v.y = fmaxf(acc[r][1], 0.f);
        v.z = fmaxf(acc[r][2], 0.f);
        v.w = fmaxf(acc[r][3], 0.f);
        *(float4*)&Z[(ty + 16 * r) * 68 + 4 * tx] = v;
    }
    __syncthreads();

    {
        float4 b = *(const float4*)(b2g + layer * 64 + 4 * tx);
        #pragma unroll
        for (int r = 0; r < 8; ++r) {
            acc[r][0] = b.x; acc[r][1] = b.y; acc[r][2] = b.z; acc[r][3] = b.w;
        }
    }
    #pragma unroll 4
    for (int k = 0; k < 64; ++k) {
        float4 w = *(const float4*)(W2 + k * 64 + 4 * tx);
        #pragma unroll
        for (int r = 0; r < 8; ++r) {
            float a = Z[(ty + 16 * r) * 68 + k];
            acc[r][0] = fmaf(a, w.x, acc[r][0]);
            acc[r][1] = fmaf(a, w.y, acc[r][1]);
            acc[r][2] = fmaf(a, w.z, acc[r][2]);
            acc[r][3] = fmaf(a, w.w, acc[r][3]);
        }
    }
    #pragma unroll
    for (int r = 0; r < 8; ++r) {
        acc[r][0] = fmaxf(acc[r][0], 0.f);
        acc[r][1] = fmaxf(acc[r][1], 0.f);
        acc[r][2] = fmaxf(acc[r][2], 0.f);
        acc[r][3] = fmaxf(acc[r][3], 0.f);
    }

    {
        float s0 = 0.f, s1 = 0.f, s2 = 0.f, s3 = 0.f;
        float q0 = 0.f, q1 = 0.f, q2 = 0.f, q3 = 0.f;
        #pragma unroll
        for (int r = 0; r < 8; ++r) {
            if (base + ty + 16 * r < n) {
                s0 += acc[r][0]; q0 += acc[r][0] * acc[r][0];
                s1 += acc[r][1]; q1 += acc[r][1] * acc[r][1];
                s2 += acc[r][2]; q2 += acc[r][2] * acc[r][2];
                s3 += acc[r][3]; q3 += acc[r][3] * acc[r][3];
            }
        }
        atomicAdd(&sS[4 * tx + 0], s0); atomicAdd(&sQ[4 * tx + 0], q0);
        atomicAdd(&sS[4 * tx + 1], s1); atomicAdd(&sQ[4 * tx + 1], q1);
        atomicAdd(&sS[4 * tx + 2], s2); atomicAdd(&sQ[4 * tx + 2], q2);
        atomicAdd(&sS[4 * tx + 3], s3); atomicAdd(&sQ[4 * tx + 3], q3);
    }

    #pragma unroll
    for (int r = 0; r < 8; ++r) {
        int row = base + ty + 16 * r;
        if (row < n) {
            ushort4 o;
            o.x = f2bf(acc[r][0]); o.y = f2bf(acc[r][1]);
            o.z = f2bf(acc[r][2]); o.w = f2bf(acc[r][3]);
            *(ushort4*)(z16 + (size_t)row * 64 + 4 * tx) = o;
        }
    }
    __syncthreads();
    if (tid < 64) {
        atomicAdd(&stats[layer * 128 + tid], sS[tid]);
        atomicAdd(&stats[layer * 128 + 64 + tid], sQ[tid]);
    }
}

// ---------------- BN finalize ----------------
__global__ void gin_bnfin(const float* __restrict__ stats, const float* __restrict__ gammas,
                          const float* __restrict__ betas, float* __restrict__ ss,
                          int layer, float n) {
    int f = threadIdx.x;  // 64
    float mu = stats[layer * 128 + f] / n;
    float var = stats[layer * 128 + 64 + f] / n - mu * mu;
    float rs = rsqrtf(var + 1e-5f);
    float g = gammas[layer * 64 + f];
    float b = betas[layer * 64 + f];
    ss[layer * 128 + f] = g * rs;
    ss[layer * 128 + 64 + f] = b - g * rs * mu;
}

// ---------------- final linear with fused BN+relu on bf16 input ----------------
__global__ __launch_bounds__(256) void gin_lin(const unsigned short* __restrict__ zin,
                                               const float* __restrict__ ss,
                                               const float* __restrict__ lw,
                                               const float* __restrict__ lb,
                                               float* __restrict__ out, int n) {
    __shared__ float Z[128 * 68];
    int tid = threadIdx.x;
    int base = blockIdx.x * 128;
    {
        const ushort4* __restrict__ src = (const ushort4*)(zin + (size_t)base * 64);
        #pragma unroll
        for (int it = 0; it < 8; ++it) {
            int idx4 = it * 256 + tid;
            int row = idx4 >> 4, c = (idx4 & 15) * 4;
            float4 v = make_float4(0.f, 0.f, 0.f, 0.f);
            if (base + row < n) {
                ushort4 u = src[idx4];
                v = make_float4(bf2f(u.x), bf2f(u.y), bf2f(u.z), bf2f(u.w));
            }
            float4 sc = *(const float4*)(ss + 256 + c);
            float4 sh = *(const float4*)(ss + 256 + 64 + c);
            float4 r;
            r.x = fmaxf(fmaf(v.x, sc.x, sh.x), 0.f);
            r.y = fmaxf(fmaf(v.y, sc.y, sh.y), 0.f);
            r.z = fmaxf(fmaf(v.z, sc.z, sh.z), 0.f);
            r.w = fmaxf(fmaf(v.w, sc.w, sh.w), 0.f);
            *(float4*)&Z[row * 68 + c] = r;
        }
    }
    __syncthreads();
    int tx = tid & 7, ty = tid >> 3;  // 8 x 32
    float acc[4][4];
    {
        float4 b = *(const float4*)(lb + 4 * tx);
        #pragma unroll
        for (int r = 0; r < 4; ++r) {
            acc[r][0] = b.x; acc[r][1] = b.y; acc[r][2] = b.z; acc[r][3] = b.w;
        }
    }
    #pragma unroll 4
    for (int k = 0; k < 64; ++k) {
        float4 w = *(const float4*)(lw + k * 32 + 4 * tx);
        #pragma unroll
        for (int r = 0; r < 4; ++r) {
            float a = Z[(ty + 32 * r) * 68 + k];
            acc[r][0] = fmaf(a, w.x, acc[r][0]);
            acc[r][1] = fmaf(a, w.y, acc[r][1]);
            acc[r][2] = fmaf(a, w.z, acc[r][2]);
            acc[r][3] = fmaf(a, w.w, acc[r][3]);
        }
    }
    #pragma unroll
    for (int r = 0; r < 4; ++r) {
        int row = base + ty + 32 * r;
        if (row < n) {
            float4 v;
            v.x = acc[r][0]; v.y = acc[r][1]; v.z = acc[r][2]; v.w = acc[r][3];
            *(float4*)(out + (size_t)row * 32 + 4 * tx) = v;
        }
    }
}

extern "C" void kernel_launch(void* const* d_in, const int* in_sizes, int n_in,
                              void* d_out, int out_size, void* d_ws, size_t ws_size,
                              hipStream_t stream) {
    const float* x      = (const float*)d_in[0];
    const void*  edge   = d_in[1];
    const float* W1s    = (const float*)d_in[2];
    const float* b1s    = (const float*)d_in[3];
    const float* W2s    = (const float*)d_in[4];
    const float* b2s    = (const float*)d_in[5];
    const float* gammas = (const float*)d_in[6];
    const float* betas  = (const float*)d_in[7];
    const float* epss   = (const float*)d_in[8];
    const float* lin_w  = (const float*)d_in[9];
    const float* lin_b  = (const float*)d_in[10];
    float* out = (float*)d_out;

    const int N = in_sizes[0] / 64;
    const int E = in_sizes[1] / 2;
    const int NB = (N + 511) >> 9;  // coarse buckets

    char* w = (char*)d_ws;
    auto take = [&](size_t bytes) {
        char* p = w;
        w += (bytes + 255) & ~(size_t)255;
        return p;
    };
    float*          A    = (float*)take((size_t)N * 64 * 4);          // gather out (fp32)
    unsigned short* zb   = (unsigned short*)take((size_t)N * 64 * 2); // bf16 h (also x16)
    int*   col     = (int*)take((size_t)E * 4);
    int*   rowptr  = (int*)take((size_t)(N + 1) * 4);
    int*   cbcnt   = (int*)take((size_t)NBMAX * 4);
    int*   cbbase  = (int*)take((size_t)(NBMAX + 1) * 4);
    int*   cbcur   = (int*)take((size_t)NBMAX * 4);
    float* stats   = (float*)take(3 * 128 * 4);
    float* ss      = (float*)take(3 * 128 * 4);
    int*   flag    = (int*)take(4);
    // lifetime aliases:
    //   ebuf (E*8 bytes) lives in A — consumed by gin_build before gather L0 writes A
    //   x16 lives in zb — consumed by gather L0 before mlp L0 writes zb
    uint2*          ebuf = (uint2*)A;
    unsigned short* x16  = zb;

    gin_detect<<<1, 1, 0, stream>>>(edge, flag, E);
    hipMemsetAsync(cbcnt, 0, (size_t)NB * 4, stream);
    hipMemsetAsync(stats, 0, 3 * 128 * 4, stream);
    gin_x16<<<(N * 16 + 255) / 256, 256, 0, stream>>>(x, x16, N * 16);
    gin_cbhist<<<256, 256, 0, stream>>>(edge, flag, cbcnt, E, NB);
    gin_cbscan<<<1, 256, 0, stream>>>(cbcnt, cbbase, cbcur, NB, rowptr, N, E);
    gin_binscatter<<<(E + CHB - 1) / CHB, 256, 0, stream>>>(edge, flag, cbcur, ebuf, E, NB);
    gin_build<<<NB, 256, 0, stream>>>(ebuf, cbbase, rowptr, col, N);

    const int gGather = (N + 3) / 4;
    const int gMlp    = (N + 127) / 128;

    for (int L = 0; L < 3; ++L) {
        const unsigned short* zin = (L == 0) ? x16 : zb;
        gin_gather<<<gGather, 256, 0, stream>>>(zin, rowptr, col, epss, ss, L,
                                                (L > 0) ? 1 : 0, A, N);
        gin_mlp<<<gMlp, 256, 0, stream>>>(A, zb, W1s, b1s, W2s, b2s, stats, L, N);
        gin_bnfin<<<1, 64, 0, stream>>>(stats, gammas, betas, ss, L, (float)N);
    }
    gin_lin<<<gMlp, 256, 0, stream>>>(zb, ss, lin_w, lin_b, out, N);
}